// Round 11
// baseline (65.354 us; speedup 1.0000x reference)
//
#include <hip/hip_runtime.h>

// Problem constants (from reference)
#define NB 4
#define S_OUT 32                                  // 128 / 4 (two 2x pools fused)
#define NC 64
#define OUT_CELLS (NB * S_OUT * S_OUT * S_OUT)    // 131072
#define OUT_ELEMS (OUT_CELLS * NC)                // 8388608 floats
#define NGROUPS (OUT_CELLS / 4)                   // 32768 (4 cells per wave)
#define CAP 16                                    // slots per cell (lambda=3.8, P(n>16)~7e-7)
#define OVF_CAP 65536
#define GATHER_BLOCKS (NGROUPS / 4)               // 8192 blocks: 1 group per wave

typedef float floatx4 __attribute__((ext_vector_type(4)));   // native vec for nt-store

// ---------- gather path ----------

// Zeroes cnt[OUT_CELLS] + ovf counter (replaces rocclr fillBufferAligned).
__global__ __launch_bounds__(256) void zero_kernel(uint4* __restrict__ cnt4,
                                                   int* __restrict__ ovf_cnt) {
    int i = blockIdx.x * blockDim.x + threadIdx.x;
    cnt4[i] = make_uint4(0u, 0u, 0u, 0u);   // grid exactly covers OUT_CELLS ints
    if (i == 0) *ovf_cnt = 0;
}

// Transposed list: list_T[slot][cell]. Slot-plane stride = OUT_CELLS dwords.
__global__ void fill_kernel(const int4* __restrict__ coors,
                            int* __restrict__ cnt,
                            int* __restrict__ list_t,
                            int* __restrict__ ovf_cnt,
                            int* __restrict__ ovf,
                            int n_pts) {
    int p = blockIdx.x * blockDim.x + threadIdx.x;
    if (p >= n_pts) return;
    int4 co = coors[p];
    int cell = ((co.x * S_OUT + (co.y >> 2)) * S_OUT + (co.z >> 2)) * S_OUT + (co.w >> 2);
    int slot = atomicAdd(&cnt[cell], 1);
    if (slot < CAP) {
        list_t[slot * OUT_CELLS + cell] = p;   // transposed store
    } else {
        int o = atomicAdd(ovf_cnt, 1);
        if (o < OVF_CAP) ovf[o] = p;           // owner group folds these in gather
    }
}

// One group (4 cells) per wave; 16-lane group q = lane>>4 owns cell (wid*4+q);
// lane holds channel quad cl=(lane&15)*4. R11 change: NO __shfl anywhere —
// slot ids come from broadcast VMEM loads of the transposed list (16 lanes
// read the same dword; the wave's 4 dwords per slot are 16 contiguous bytes).
// The 8 slot->feature chains are fully independent 2-deep load chains.
__global__ __launch_bounds__(256) void gather_kernel(
        const float* __restrict__ features,
        const int4* __restrict__ coors,
        const int* __restrict__ cnt,
        const int* __restrict__ list_t,
        const int* __restrict__ ovf_cnt,
        const int* __restrict__ ovf,
        float* __restrict__ out) {
    const int lane = threadIdx.x & 63;
    const int wid  = (blockIdx.x * blockDim.x + threadIdx.x) >> 6;
    const int cl   = (lane & 15) << 2;     // channel quad base
    const int cell = (wid << 2) + (lane >> 4);   // group's cell (uniform per 16 lanes)

    int n = cnt[cell];                     // broadcast load
    int m = n < CAP ? n : CAP;
    float4 acc = make_float4(-INFINITY, -INFINITY, -INFINITY, -INFINITY);

    #pragma unroll
    for (int s = 0; s < 8; ++s) {
        if (s < m) {                       // uniform per 16-lane group
            int p = list_t[s * OUT_CELLS + cell];          // broadcast dword
            const float4 f = *(const float4*)(features + (size_t)p * NC + cl);
            acc.x = fmaxf(acc.x, f.x); acc.y = fmaxf(acc.y, f.y);
            acc.z = fmaxf(acc.z, f.z); acc.w = fmaxf(acc.w, f.w);
        }
    }
    if (__builtin_expect(m > 8, 0)) {      // uncommon tail (P ~ 1.3%)
        for (int s = 8; s < m; ++s) {
            int p = list_t[s * OUT_CELLS + cell];
            const float4 f = *(const float4*)(features + (size_t)p * NC + cl);
            acc.x = fmaxf(acc.x, f.x); acc.y = fmaxf(acc.y, f.y);
            acc.z = fmaxf(acc.z, f.z); acc.w = fmaxf(acc.w, f.w);
        }
    }
    if (__builtin_expect(__any(n > CAP), 0)) {   // owner-side overflow fold
        int novf = *ovf_cnt;
        if (novf > OVF_CAP) novf = OVF_CAP;
        for (int i = 0; i < novf; ++i) {
            int p = ovf[i];                // broadcast load
            int4 co = coors[p];
            int cellp = ((co.x * S_OUT + (co.y >> 2)) * S_OUT + (co.z >> 2)) * S_OUT + (co.w >> 2);
            if (n > CAP && cellp == cell) {
                const float4 f = *(const float4*)(features + (size_t)p * NC + cl);
                acc.x = fmaxf(acc.x, f.x); acc.y = fmaxf(acc.y, f.y);
                acc.z = fmaxf(acc.z, f.z); acc.w = fmaxf(acc.w, f.w);
            }
        }
    }
    if (n == 0) acc = make_float4(0.f, 0.f, 0.f, 0.f);
    floatx4 accv = { acc.x, acc.y, acc.z, acc.w };
    __builtin_nontemporal_store(accv, (floatx4*)(out + ((size_t)wid << 8) + (size_t)lane * 4));
}

// ---------- fallback path (R1's working atomicMax scatter) ----------

__device__ __forceinline__ unsigned flip_f(float f) {
    unsigned u = __float_as_uint(f);
    return (u & 0x80000000u) ? ~u : (u | 0x80000000u);
}
__device__ __forceinline__ float unflip_f(unsigned u) {
    unsigned v = (u & 0x80000000u) ? (u & 0x7FFFFFFFu) : ~u;
    return __uint_as_float(v);
}

__global__ void init_kernel(uint4* __restrict__ out4, int n4) {
    int i = blockIdx.x * blockDim.x + threadIdx.x;
    int stride = gridDim.x * blockDim.x;
    uint4 z = make_uint4(0u, 0u, 0u, 0u);
    for (; i < n4; i += stride) out4[i] = z;
}

__global__ void scatter_kernel(const float* __restrict__ features,
                               const int4* __restrict__ coors,
                               unsigned* __restrict__ acc, int n_pts) {
    int gid = blockIdx.x * blockDim.x + threadIdx.x;
    int p = gid >> 6;
    int c = threadIdx.x & 63;
    if (p >= n_pts) return;
    int4 co = coors[p];
    int cell = ((co.x * S_OUT + (co.y >> 2)) * S_OUT + (co.z >> 2)) * S_OUT + (co.w >> 2);
    atomicMax(acc + (size_t)cell * NC + c, flip_f(features[(size_t)p * NC + c]));
}

__global__ void finalize_kernel(unsigned* __restrict__ acc, int n) {
    int i = blockIdx.x * blockDim.x + threadIdx.x;
    int stride = gridDim.x * blockDim.x;
    for (; i < n; i += stride) {
        unsigned u = acc[i];
        ((float*)acc)[i] = (u == 0u) ? 0.0f : unflip_f(u);
    }
}

extern "C" void kernel_launch(void* const* d_in, const int* in_sizes, int n_in,
                              void* d_out, int out_size, void* d_ws, size_t ws_size,
                              hipStream_t stream) {
    const float* features = (const float*)d_in[0];
    const int4*  coors    = (const int4*)d_in[1];
    int n_pts = in_sizes[0] / NC;   // 500000

    // workspace layout
    const size_t off_cnt  = 0;
    const size_t cnt_b    = (size_t)OUT_CELLS * 4;             // 524288
    const size_t off_ovfc = cnt_b;                             // 4B counter
    const size_t off_ovf  = off_ovfc + 256;
    const size_t off_list = off_ovf + (size_t)OVF_CAP * 4;
    const size_t need     = off_list + (size_t)OUT_CELLS * CAP * 4;   // ~9 MB

    if (ws_size >= need) {
        char* ws = (char*)d_ws;
        int* cnt     = (int*)(ws + off_cnt);
        int* ovf_cnt = (int*)(ws + off_ovfc);
        int* ovf     = (int*)(ws + off_ovf);
        int* list_t  = (int*)(ws + off_list);
        float* out   = (float*)d_out;

        // zero counters with our own kernel
        {
            int n4 = OUT_CELLS * 4 / 16;          // 32768 uint4s
            zero_kernel<<<n4 / 256, 256, 0, stream>>>((uint4*)cnt, ovf_cnt);
        }
        // build per-cell point lists (transposed layout)
        {
            int block = 256;
            int grid = (n_pts + block - 1) / block;
            fill_kernel<<<grid, block, 0, stream>>>(coors, cnt, list_t, ovf_cnt, ovf, n_pts);
        }
        // gather max: 1 group (4 cells) per wave, shfl-free transposed-list reads
        gather_kernel<<<GATHER_BLOCKS, 256, 0, stream>>>(features, coors, cnt, list_t,
                                                         ovf_cnt, ovf, out);
    } else {
        // fallback: R1 atomic scatter path
        unsigned* acc = (unsigned*)d_out;
        init_kernel<<<2048, 256, 0, stream>>>((uint4*)d_out, OUT_ELEMS / 4);
        int grid = (n_pts * 64 + 255) / 256;
        scatter_kernel<<<grid, 256, 0, stream>>>(features, coors, acc, n_pts);
        finalize_kernel<<<2048, 256, 0, stream>>>(acc, OUT_ELEMS);
    }
}

// Round 12
// 64.941 us; speedup vs baseline: 1.0064x; 1.0064x over previous
//
#include <hip/hip_runtime.h>

// Problem constants (from reference)
#define NB 4
#define S_OUT 32                                  // 128 / 4 (two 2x pools fused)
#define NC 64
#define OUT_CELLS (NB * S_OUT * S_OUT * S_OUT)    // 131072
#define OUT_ELEMS (OUT_CELLS * NC)                // 8388608 floats
#define NGROUPS (OUT_CELLS / 4)                   // 32768 (4 cells per wave)
#define CAP 16                                    // slots per cell (lambda=3.8, P(n>16)~7e-7)
#define OVF_CAP 65536

typedef float floatx4 __attribute__((ext_vector_type(4)));   // native vec for nt-store

// ---------- gather path ----------

// Zeroes cnt[OUT_CELLS] + ovf counter (replaces rocclr fillBufferAligned).
__global__ __launch_bounds__(256) void zero_kernel(uint4* __restrict__ cnt4,
                                                   int* __restrict__ ovf_cnt) {
    int i = blockIdx.x * blockDim.x + threadIdx.x;
    cnt4[i] = make_uint4(0u, 0u, 0u, 0u);   // grid exactly covers OUT_CELLS ints
    if (i == 0) *ovf_cnt = 0;
}

// R12: fill also STREAM-TOUCHES the features array (sequential uint4 reads at
// full HBM BW) to warm the 256MB L3 before gather's random 256B reads.
// Touch loads are issued first (independent, stay in flight over the atomic
// work); asm volatile keep-alive prevents DCE (rule #17).
__global__ void fill_kernel(const int4* __restrict__ coors,
                            const uint4* __restrict__ feat4,   // features as uint4
                            int* __restrict__ cnt,
                            int* __restrict__ list,
                            int* __restrict__ ovf_cnt,
                            int* __restrict__ ovf,
                            int n_pts) {
    int tid = blockIdx.x * blockDim.x + threadIdx.x;
    int nthreads = gridDim.x * blockDim.x;

    // ---- L3 warm: sequential touch of all feature bytes (2M uint4s) ----
    const int NF4 = (500000 * NC * 4) / 16;       // 8,000,000 floats -> 2,000,000 uint4
    uint4 t0 = make_uint4(0,0,0,0), t1 = t0, t2 = t0, t3 = t0, t4 = t0;
    {
        int i = tid;
        if (i < NF4)                 { t0 = feat4[i]; i += nthreads; }
        if (i < NF4)                 { t1 = feat4[i]; i += nthreads; }
        if (i < NF4)                 { t2 = feat4[i]; i += nthreads; }
        if (i < NF4)                 { t3 = feat4[i]; i += nthreads; }
        if (i < NF4)                 { t4 = feat4[i]; }
    }

    // ---- binning work (unchanged from R10) ----
    if (tid < n_pts) {
        int4 co = coors[tid];
        int cell = ((co.x * S_OUT + (co.y >> 2)) * S_OUT + (co.z >> 2)) * S_OUT + (co.w >> 2);
        int slot = atomicAdd(&cnt[cell], 1);
        if (slot < CAP) {
            list[cell * CAP + slot] = tid;
        } else {
            int o = atomicAdd(ovf_cnt, 1);
            if (o < OVF_CAP) ovf[o] = tid;   // owner group folds these in gather
        }
    }

    // keep the touch loads alive without using their values
    asm volatile("" :: "v"(t0.x), "v"(t1.x), "v"(t2.x), "v"(t3.x), "v"(t4.x));
}

// 4 cells per wave; 16-lane group q = lane>>4 owns cell (g*4+q); lane holds
// channel quad cl=(lane&15)*4. Grid-stride with next-iteration metadata
// prefetch; exec-masked slot loads (R9/R10 config).
__global__ __launch_bounds__(256) void gather_kernel(
        const float* __restrict__ features,
        const int4* __restrict__ coors,
        const int* __restrict__ cnt,
        const int* __restrict__ list,
        const int* __restrict__ ovf_cnt,
        const int* __restrict__ ovf,
        float* __restrict__ out) {
    const int lane  = threadIdx.x & 63;
    const int wid   = (blockIdx.x * blockDim.x + threadIdx.x) >> 6;
    const int nw    = (gridDim.x * blockDim.x) >> 6;
    const int cl    = (lane & 15) << 2;    // channel quad base
    const int sbase = lane & 48;           // group's slot base lane
    const int qsel  = lane >> 4;           // group index 0..3

    int g = wid;
    if (g >= NGROUPS) return;

    // prefetch first group's metadata
    int n_pf  = cnt[(g << 2) + qsel];
    int pl_pf = list[((size_t)g << 6) + lane];   // 4 cells x 16 slots = 64 dwords

    while (true) {
        int n  = n_pf;
        int pl = pl_pf;
        int gn = g + nw;
        if (gn < NGROUPS) {                       // prefetch next iteration
            n_pf  = cnt[(gn << 2) + qsel];
            pl_pf = list[((size_t)gn << 6) + lane];
        }

        int m = n < CAP ? n : CAP;
        float4 acc = make_float4(-INFINITY, -INFINITY, -INFINITY, -INFINITY);

        #pragma unroll
        for (int s = 0; s < 8; ++s) {
            int p = __shfl(pl, sbase + s);
            if (s < m) {                          // exec-masked: inactive lanes
                const float4 f = *(const float4*)(features + (size_t)p * NC + cl);
                acc.x = fmaxf(acc.x, f.x); acc.y = fmaxf(acc.y, f.y);
                acc.z = fmaxf(acc.z, f.z); acc.w = fmaxf(acc.w, f.w);
            }
        }
        if (m > 8) {                              // uncommon tail (P ~ 1.3%)
            for (int s = 8; s < m; ++s) {
                int p = __shfl(pl, sbase + s);
                const float4 f = *(const float4*)(features + (size_t)p * NC + cl);
                acc.x = fmaxf(acc.x, f.x); acc.y = fmaxf(acc.y, f.y);
                acc.z = fmaxf(acc.z, f.z); acc.w = fmaxf(acc.w, f.w);
            }
        }
        if (__builtin_expect(__any(n > CAP), 0)) {   // owner-side overflow fold
            int mycell = (g << 2) + qsel;
            int novf = *ovf_cnt;
            if (novf > OVF_CAP) novf = OVF_CAP;
            for (int i = 0; i < novf; ++i) {
                int p = ovf[i];                   // broadcast load
                int4 co = coors[p];
                int cellp = ((co.x * S_OUT + (co.y >> 2)) * S_OUT + (co.z >> 2)) * S_OUT + (co.w >> 2);
                if (n > CAP && cellp == mycell) {
                    const float4 f = *(const float4*)(features + (size_t)p * NC + cl);
                    acc.x = fmaxf(acc.x, f.x); acc.y = fmaxf(acc.y, f.y);
                    acc.z = fmaxf(acc.z, f.z); acc.w = fmaxf(acc.w, f.w);
                }
            }
        }
        if (n == 0) acc = make_float4(0.f, 0.f, 0.f, 0.f);
        floatx4 accv = { acc.x, acc.y, acc.z, acc.w };
        __builtin_nontemporal_store(accv, (floatx4*)(out + ((size_t)g << 8) + (size_t)lane * 4));

        if (gn >= NGROUPS) break;
        g = gn;
    }
}

// ---------- fallback path (R1's working atomicMax scatter) ----------

__device__ __forceinline__ unsigned flip_f(float f) {
    unsigned u = __float_as_uint(f);
    return (u & 0x80000000u) ? ~u : (u | 0x80000000u);
}
__device__ __forceinline__ float unflip_f(unsigned u) {
    unsigned v = (u & 0x80000000u) ? (u & 0x7FFFFFFFu) : ~u;
    return __uint_as_float(v);
}

__global__ void init_kernel(uint4* __restrict__ out4, int n4) {
    int i = blockIdx.x * blockDim.x + threadIdx.x;
    int stride = gridDim.x * blockDim.x;
    uint4 z = make_uint4(0u, 0u, 0u, 0u);
    for (; i < n4; i += stride) out4[i] = z;
}

__global__ void scatter_kernel(const float* __restrict__ features,
                               const int4* __restrict__ coors,
                               unsigned* __restrict__ acc, int n_pts) {
    int gid = blockIdx.x * blockDim.x + threadIdx.x;
    int p = gid >> 6;
    int c = threadIdx.x & 63;
    if (p >= n_pts) return;
    int4 co = coors[p];
    int cell = ((co.x * S_OUT + (co.y >> 2)) * S_OUT + (co.z >> 2)) * S_OUT + (co.w >> 2);
    atomicMax(acc + (size_t)cell * NC + c, flip_f(features[(size_t)p * NC + c]));
}

__global__ void finalize_kernel(unsigned* __restrict__ acc, int n) {
    int i = blockIdx.x * blockDim.x + threadIdx.x;
    int stride = gridDim.x * blockDim.x;
    for (; i < n; i += stride) {
        unsigned u = acc[i];
        ((float*)acc)[i] = (u == 0u) ? 0.0f : unflip_f(u);
    }
}

extern "C" void kernel_launch(void* const* d_in, const int* in_sizes, int n_in,
                              void* d_out, int out_size, void* d_ws, size_t ws_size,
                              hipStream_t stream) {
    const float* features = (const float*)d_in[0];
    const int4*  coors    = (const int4*)d_in[1];
    int n_pts = in_sizes[0] / NC;   // 500000

    // workspace layout
    const size_t off_cnt  = 0;
    const size_t cnt_b    = (size_t)OUT_CELLS * 4;             // 524288
    const size_t off_ovfc = cnt_b;                             // 4B counter
    const size_t off_ovf  = off_ovfc + 256;
    const size_t off_list = off_ovf + (size_t)OVF_CAP * 4;
    const size_t need     = off_list + (size_t)OUT_CELLS * CAP * 4;   // ~9 MB

    if (ws_size >= need) {
        char* ws = (char*)d_ws;
        int* cnt     = (int*)(ws + off_cnt);
        int* ovf_cnt = (int*)(ws + off_ovfc);
        int* ovf     = (int*)(ws + off_ovf);
        int* list    = (int*)(ws + off_list);
        float* out   = (float*)d_out;

        // zero counters with our own kernel
        {
            int n4 = OUT_CELLS * 4 / 16;          // 32768 uint4s
            zero_kernel<<<n4 / 256, 256, 0, stream>>>((uint4*)cnt, ovf_cnt);
        }
        // build per-cell point lists + L3-warm the features (streaming touch)
        {
            int block = 256;
            int grid = (n_pts + block - 1) / block;
            fill_kernel<<<grid, block, 0, stream>>>(coors, (const uint4*)features,
                                                    cnt, list, ovf_cnt, ovf, n_pts);
        }
        // gather max (+ owner-side overflow fold): 4 cells/wave, masked loads
        {
            int block = 256;
            int grid = 2048;    // 8192 waves, 4 groups each
            gather_kernel<<<grid, block, 0, stream>>>(features, coors, cnt, list,
                                                      ovf_cnt, ovf, out);
        }
    } else {
        // fallback: R1 atomic scatter path
        unsigned* acc = (unsigned*)d_out;
        init_kernel<<<2048, 256, 0, stream>>>((uint4*)d_out, OUT_ELEMS / 4);
        int grid = (n_pts * 64 + 255) / 256;
        scatter_kernel<<<grid, 256, 0, stream>>>(features, coors, acc, n_pts);
        finalize_kernel<<<2048, 256, 0, stream>>>(acc, OUT_ELEMS);
    }
}